// Round 15
// baseline (649.677 us; speedup 1.0000x reference)
//
#include <hip/hip_runtime.h>
#include <hip/hip_bf16.h>
#include <math.h>

#define NODES 73728   // B*T*N = 128*64*9
#define BB    128
#define TT    64
#define NN    9
#define LDX   256
#define E_REAL 203648.0f
#define NARR  33

typedef __hip_bfloat16 bf16;
typedef _Float16 half8 __attribute__((ext_vector_type(8)));
typedef _Float16 half4 __attribute__((ext_vector_type(4)));
typedef float f32x4 __attribute__((ext_vector_type(4)));

__device__ __forceinline__ float bfdec(unsigned short u) {
  return __uint_as_float(((unsigned)u) << 16);
}
__device__ __forceinline__ unsigned short f2bf(float x) {
  bf16 h = __float2bfloat16(x);
  return *(unsigned short*)&h;
}
__device__ __forceinline__ float4 ldbf4(const bf16* p) {  // 8B-aligned
  ushort4 u = *(const ushort4*)p;
  float4 f;
  f.x = bfdec(u.x); f.y = bfdec(u.y); f.z = bfdec(u.z); f.w = bfdec(u.w);
  return f;
}

// ---------------- dtype detector ----------------
__global__ __launch_bounds__(256) void detect_kernel(const unsigned short* __restrict__ raw,
                                                     float* __restrict__ flag) {
  __shared__ float sm[256];
  float mx = 0.f;
  for (int i = threadIdx.x; i < 2048; i += 256) mx = fmaxf(mx, fabsf(bfdec(raw[2 * i])));
  sm[threadIdx.x] = mx;
  __syncthreads();
  for (int s = 128; s > 0; s >>= 1) {
    if (threadIdx.x < s) sm[threadIdx.x] = fmaxf(sm[threadIdx.x], sm[threadIdx.x + s]);
    __syncthreads();
  }
  if (threadIdx.x == 0) flag[0] = (sm[0] > 1000.f) ? 1.f : 0.f;
}

// ---------------- convert all inputs to fp32 params region ----------------
struct CvtArgs { const void* src[NARR]; int size[NARR]; int off[NARR]; };

__global__ __launch_bounds__(256) void convert_kernel(CvtArgs a, const float* __restrict__ flag,
                                                      float* __restrict__ dst) {
  int i = blockIdx.y;
  int sz = a.size[i];
  bool isf32 = flag[0] > 0.5f;
  const float* sf = (const float*)a.src[i];
  const unsigned short* sh = (const unsigned short*)a.src[i];
  float* d = dst + a.off[i];
  for (int j = blockIdx.x * 256 + threadIdx.x; j < sz; j += gridDim.x * 256)
    d[j] = isf32 ? sf[j] : bfdec(sh[j]);
}

// ---------------- f16 shadow of the whole param region ----------------
__global__ __launch_bounds__(256) void tohalf_kernel(const float* __restrict__ prm,
                                                     _Float16* __restrict__ dst, int n) {
  int i = blockIdx.x * 256 + threadIdx.x;
  if (i < n) dst[i] = (_Float16)prm[i];
}

// ---------------- encoder (one block per node, thread d) ----------------
__global__ __launch_bounds__(128) void encoder_simple(const float* __restrict__ nf,
    const float* __restrict__ encW, const float* __restrict__ encb, _Float16* __restrict__ Xh) {
  int v = blockIdx.x, d = threadIdx.x, n = v % NN;
  float f[14];
#pragma unroll
  for (int i = 0; i < 10; i++) f[i] = nf[(size_t)v * 10 + i];
  f[10] = (n < 7) ? 1.f : 0.f;
  f[11] = (n == 7) ? 1.f : 0.f;
  f[12] = (n == 8) ? 1.f : 0.f;
  f[13] = fabsf((float)(n - 7));
  const float* w = &encW[((size_t)n * 128 + d) * 14];
  float s = encb[n * 128 + d];
#pragma unroll
  for (int i = 0; i < 14; i++) s = fmaf(f[i], w[i], s);
  Xh[(size_t)v * LDX + d] = (_Float16)s;
}

// ---------------- fill ----------------
__global__ __launch_bounds__(256) void fill_kernel(const float* __restrict__ nf,
                                                   float* __restrict__ fill) {
  __shared__ float sx[256], sy[256], sz[256];
  int tid = threadIdx.x;
  float ax = 0.f, ay = 0.f, az = 0.f;
  for (int p = tid; p < BB * NN; p += 256) {
    int b = p / NN, n = p - b * NN;
    size_t late  = (((size_t)b * TT + (TT - 1)) * NN + n) * 10;
    size_t early = (((size_t)b * TT) * NN + n) * 10;
    ax += nf[late + 0] - nf[early + 0];
    ay += nf[late + 1] - nf[early + 1];
    az += nf[late + 2] - nf[early + 2];
  }
  sx[tid] = ax; sy[tid] = ay; sz[tid] = az;
  __syncthreads();
  for (int s = 128; s > 0; s >>= 1) {
    if (tid < s) { sx[tid] += sx[tid + s]; sy[tid] += sy[tid + s]; sz[tid] += sz[tid + s]; }
    __syncthreads();
  }
  if (tid == 0) { fill[0] = sx[0] / E_REAL; fill[1] = sy[0] / E_REAL; fill[2] = sz[0] / E_REAL; }
}

// ================= MFMA GEMM: 128 rows x 256 cols per block, 512 threads (8 waves) =================
// Wave w: row-group rg=w>>2 (64 rows), col-group cg=w&3 (64 cols): 4x4 16x16 tiles, acc 64 VGPR.
// B tile staged once per 128 rows (half the traffic of 64-row blocks).
// LDS: staging 30720 B union epi[64][256] (32768 B) -> block = 32768 B.
#define LDA 40
struct GemmSh { _Float16 A[128 * LDA]; _Float16 B[256 * LDA]; };   // 10240 + 20480 B

__device__ __forceinline__ void mfma_gemm(const _Float16* __restrict__ x,
    const _Float16* __restrict__ W, int K, int row0, int tid,
    _Float16* shA, _Float16* shB, f32x4 (&acc)[4][4]) {
  int lane = tid & 63, wave = tid >> 6;
  int rg = wave >> 2, cg = wave & 3;
  int quad = lane >> 4, mrow = lane & 15;
  int ar = tid >> 2, ak = (tid & 3) << 3;     // A: 128 rows x 32 cols, 1 half8/thread
  int br = tid >> 1, bc = (tid & 1) << 4;     // B: 256 rows x 32 cols, 2 half8/thread
  for (int k0 = 0; k0 < K; k0 += 32) {
    *(half8*)&shA[ar * LDA + ak] = *(const half8*)&x[(size_t)(row0 + ar) * LDX + k0 + ak];
    *(half8*)&shB[br * LDA + bc] = *(const half8*)&W[(size_t)br * K + k0 + bc];
    *(half8*)&shB[br * LDA + bc + 8] = *(const half8*)&W[(size_t)br * K + k0 + bc + 8];
    __syncthreads();
    half8 af[4], bfr[4];
#pragma unroll
    for (int rt = 0; rt < 4; rt++)
      af[rt] = *(const half8*)&shA[(rg * 64 + rt * 16 + mrow) * LDA + quad * 8];
#pragma unroll
    for (int ct = 0; ct < 4; ct++)
      bfr[ct] = *(const half8*)&shB[(cg * 64 + ct * 16 + mrow) * LDA + quad * 8];
#pragma unroll
    for (int rt = 0; rt < 4; rt++)
#pragma unroll
      for (int ct = 0; ct < 4; ct++)
        acc[rt][ct] = __builtin_amdgcn_mfma_f32_16x16x32_f16(af[rt], bfr[ct], acc[rt][ct], 0, 0, 0);
    __syncthreads();
  }
}

// phase P (0/1): waves with rg==P write their 64 rows (+bias) to epi as bf16, then barrier.
// C/D map: col=lane&15, row=quad*4+reg.
#define ACC_TO_EPI_P(EPI, BIASPTR, P)                                           \
  if ((tid >> 8) == (P)) {                                                      \
    int lane_ = tid & 63, cg_ = (tid >> 6) & 3, quad_ = lane_ >> 4, mrow_ = lane_ & 15; \
    _Pragma("unroll")                                                           \
    for (int rt = 0; rt < 4; rt++)                                              \
      _Pragma("unroll")                                                         \
      for (int ct = 0; ct < 4; ct++) {                                          \
        int col = cg_ * 64 + ct * 16 + mrow_;                                   \
        float bs_ = BIASPTR[col];                                               \
        _Pragma("unroll")                                                       \
        for (int r = 0; r < 4; r++)                                             \
          EPI[rt * 16 + quad_ * 4 + r][col] = f2bf(acc[rt][ct][r] + bs_);       \
      }                                                                         \
  }                                                                             \
  __syncthreads();

// ---------------- XL = X @ lW.T + lb -> bf16 ----------------
__global__ __launch_bounds__(512) void gemm_xl_kernel(const _Float16* __restrict__ x, int K,
    const _Float16* __restrict__ W, const float* __restrict__ bias, bf16* __restrict__ XL) {
  __shared__ union { GemmSh st; unsigned short epi[64][256]; } sh;
  int tid = threadIdx.x;
  int row0 = blockIdx.x * 128;
  f32x4 acc[4][4] = {};
  mfma_gemm(x, W, K, row0, tid, sh.st.A, sh.st.B, acc);
#pragma unroll
  for (int p = 0; p < 2; p++) {
    ACC_TO_EPI_P(sh.epi, bias, p)
    int r = tid >> 3;                       // 64 rows, 8 threads/row
#pragma unroll
    for (int j = 0; j < 8; j++) {
      int c0 = (((tid & 7) << 3) + j) << 2;
      *(ushort4*)&XL[(size_t)(row0 + p * 64 + r) * LDX + c0] = *(const ushort4*)&sh.epi[r][c0];
    }
    __syncthreads();                        // reads done before next phase overwrites
  }
}

// ---------------- fused: XR GEMM + edge logits + softmax + aggregation -> AGG[v] bf16 ----------------
__global__ __launch_bounds__(512) void logits_kernel(const _Float16* __restrict__ x, int K,
    const _Float16* __restrict__ rW, const float* __restrict__ rb,
    const bf16* __restrict__ XL, const float* __restrict__ nf, const float* __restrict__ fill,
    const float* __restrict__ att, const float* __restrict__ eW, bf16* __restrict__ AGG) {
  __shared__ union { GemmSh st; unsigned short epi[64][256]; } sh;
  int tid = threadIdx.x;
  int row0 = blockIdx.x * 128;
  f32x4 acc[4][4] = {};
  mfma_gemm(x, rW, K, row0, tid, sh.st.A, sh.st.B, acc);

  int wave = tid >> 6, lane = tid & 63;
  int cc = lane << 2;        // 4 channels/lane; 16 lanes = one head
  float attv[4], ew[4][3];
#pragma unroll
  for (int i = 0; i < 4; i++) {
    attv[i] = att[cc + i];
    ew[i][0] = eW[(cc + i) * 3 + 0];
    ew[i][1] = eW[(cc + i) * 3 + 1];
    ew[i][2] = eW[(cc + i) * 3 + 2];
  }
  float f0 = fill[0], f1 = fill[1], f2 = fill[2];
#pragma unroll
  for (int p = 0; p < 2; p++) {
    ACC_TO_EPI_P(sh.epi, rb, p)
    for (int k = 0; k < 8; k++) {           // 8 waves x 8 nodes = 64 rows per phase
      int lr = wave * 8 + k;
      int v = row0 + p * 64 + lr;
      int n = v % NN;
      int t = (v / NN) & 63;
      int srcs[4] = { v, (n > 0) ? v - 1 : v, (n < NN - 1) ? v + 1 : v, (t > 0) ? v - NN : v };
      bool valid[4] = { true, n > 0, n < NN - 1, t > 0 };
      float px = nf[(size_t)v * 10 + 0];
      float py = nf[(size_t)v * 10 + 1];
      float pz = nf[(size_t)v * 10 + 2];
      ushort4 xr4 = *(const ushort4*)&sh.epi[lr][cc];
      float xr[4] = { bfdec(xr4.x), bfdec(xr4.y), bfdec(xr4.z), bfdec(xr4.w) };
      float logit[4], xlv[4][4];
#pragma unroll
      for (int e = 0; e < 4; e++) {
        int s = srcs[e];
        float a0, a1, a2;
        if (e == 0) { a0 = f0; a1 = f1; a2 = f2; }
        else {
          a0 = px - nf[(size_t)s * 10 + 0];
          a1 = py - nf[(size_t)s * 10 + 1];
          a2 = pz - nf[(size_t)s * 10 + 2];
        }
        float4 xl = ldbf4(&XL[(size_t)s * LDX + cc]);
        xlv[e][0] = xl.x; xlv[e][1] = xl.y; xlv[e][2] = xl.z; xlv[e][3] = xl.w;
        float pp = 0.f;
#pragma unroll
        for (int i = 0; i < 4; i++) {
          float em = fmaf(ew[i][0], a0, fmaf(ew[i][1], a1, ew[i][2] * a2));
          float mv = xlv[e][i] + xr[i] + em;
          mv = (mv > 0.f) ? mv : 0.2f * mv;   // leaky_relu 0.2
          pp = fmaf(mv, attv[i], pp);
        }
        pp += __shfl_xor(pp, 1); pp += __shfl_xor(pp, 2);
        pp += __shfl_xor(pp, 4); pp += __shfl_xor(pp, 8);
        logit[e] = valid[e] ? pp : -1e30f;
      }
      float mx = fmaxf(fmaxf(logit[0], logit[1]), fmaxf(logit[2], logit[3]));
      float wv4[4], wsum = 0.f;
#pragma unroll
      for (int e = 0; e < 4; e++) { wv4[e] = __expf(logit[e] - mx); wsum += wv4[e]; }
      float inv = 1.f / wsum;
      float agg[4] = { 0.f, 0.f, 0.f, 0.f };
#pragma unroll
      for (int e = 0; e < 4; e++) {
        float w = wv4[e] * inv;                 // invalid edges: exactly 0
#pragma unroll
        for (int i = 0; i < 4; i++) agg[i] = fmaf(w, xlv[e][i], agg[i]);
      }
      ushort4 pk;
      pk.x = f2bf(agg[0]); pk.y = f2bf(agg[1]); pk.z = f2bf(agg[2]); pk.w = f2bf(agg[3]);
      *(ushort4*)&AGG[(size_t)v * LDX + cc] = pk;   // coalesced 8B/lane
    }
    __syncthreads();
  }
}

// ---------------- fused: XO = X@sW.T + bias + AGG; LN; SiLU; X f16 in-place ----------------
__global__ __launch_bounds__(512) void out_kernel(_Float16* Xh, int K,
    const _Float16* __restrict__ sW, const float* __restrict__ bias,
    const bf16* __restrict__ AGG,
    const float* __restrict__ gamma, const float* __restrict__ beta) {
  __shared__ union { GemmSh st; unsigned short epi[64][256]; } sh;
  int tid = threadIdx.x;
  int row0 = blockIdx.x * 128;
  f32x4 acc[4][4] = {};
  mfma_gemm(Xh, sW, K, row0, tid, sh.st.A, sh.st.B, acc);

  int wave = tid >> 6, lane = tid & 63;
  int cc = lane << 2;
  float gm[4], bt[4];
#pragma unroll
  for (int i = 0; i < 4; i++) { gm[i] = gamma[cc + i]; bt[i] = beta[cc + i]; }
#pragma unroll
  for (int p = 0; p < 2; p++) {
    ACC_TO_EPI_P(sh.epi, bias, p)
    for (int k = 0; k < 8; k++) {
      int lr = wave * 8 + k;
      int v = row0 + p * 64 + lr;
      ushort4 xo4 = *(const ushort4*)&sh.epi[lr][cc];
      float4 ag = ldbf4(&AGG[(size_t)v * LDX + cc]);
      float xv[4] = { bfdec(xo4.x) + ag.x, bfdec(xo4.y) + ag.y,
                      bfdec(xo4.z) + ag.z, bfdec(xo4.w) + ag.w };
      // LayerNorm over 256 channels (full-wave shuffle reduce)
      float s1 = xv[0] + xv[1] + xv[2] + xv[3];
#pragma unroll
      for (int off = 1; off < 64; off <<= 1) s1 += __shfl_xor(s1, off);
      float mu = s1 * (1.f / 256.f);
      float s2 = 0.f;
#pragma unroll
      for (int i = 0; i < 4; i++) { float d = xv[i] - mu; s2 = fmaf(d, d, s2); }
#pragma unroll
      for (int off = 1; off < 64; off <<= 1) s2 += __shfl_xor(s2, off);
      float rs = rsqrtf(s2 * (1.f / 256.f) + 1e-5f);
      half4 o;
#pragma unroll
      for (int i = 0; i < 4; i++) {
        float y = (xv[i] - mu) * rs * gm[i] + bt[i];
        o[i] = (_Float16)(y * (1.f / (1.f + __expf(-y))));   // SiLU
      }
      *(half4*)&Xh[(size_t)v * LDX + cc] = o;
    }
    __syncthreads();
  }
}

// ---------------- mean over 576 positions -> (B,256) fp32 ----------------
__global__ __launch_bounds__(256) void pool_kernel(const _Float16* __restrict__ Xh,
                                                   float* __restrict__ out) {
  int b = blockIdx.x, c = threadIdx.x;
  const _Float16* p = &Xh[(size_t)b * 576 * LDX + c];
  float s = 0.f;
  for (int i = 0; i < 576; i++) s += (float)p[(size_t)i * LDX];
  out[b * 256 + c] = s * (1.f / 576.f);
}

extern "C" void kernel_launch(void* const* d_in, const int* in_sizes, int n_in,
                              void* d_out, int out_size, void* d_ws, size_t ws_size,
                              hipStream_t stream) {
  static const int kSize[NARR] = {
    737280, 16128, 1152,
    32768, 256, 32768, 256, 256, 768, 32768, 256, 256, 256,   // layer 0 (K=128)
    65536, 256, 65536, 256, 256, 768, 65536, 256, 256, 256,   // layer 1 (K=256)
    65536, 256, 65536, 256, 256, 768, 65536, 256, 256, 256    // layer 2 (K=256)
  };
  if (n_in != NARR || out_size != BB * 256) return;
  for (int i = 0; i < NARR; i++) if (in_sizes[i] != kSize[i]) return;

  CvtArgs ca;
  int off = 0;
  for (int i = 0; i < NARR; i++) { ca.src[i] = d_in[i]; ca.size[i] = kSize[i]; ca.off[i] = off; off += kSize[i]; }
  const int PRM_ELEMS = off;   // 1,252,992

  const size_t OFF_FLAG = 0;
  const size_t OFF_FILL = 16;
  const size_t OFF_PRM  = 256;
  const size_t OFF_PRMH = OFF_PRM + (size_t)PRM_ELEMS * 4;     // f16 shadow
  const size_t OFF_AGG  = OFF_PRMH + (size_t)PRM_ELEMS * 2;
  const size_t OFF_XL   = OFF_AGG + (size_t)NODES * LDX * 2;   // AGG bf16
  const size_t OFF_XH   = OFF_XL + (size_t)NODES * LDX * 2;    // XL bf16
  const size_t NEED     = OFF_XH + (size_t)NODES * LDX * 2;    // ~115 MiB (< proven 125.3)
  if (ws_size < NEED) return;

  char* ws = (char*)d_ws;
  float*     flag = (float*)(ws + OFF_FLAG);
  float*     fill = (float*)(ws + OFF_FILL);
  float*     prm  = (float*)(ws + OFF_PRM);
  _Float16*  prmh = (_Float16*)(ws + OFF_PRMH);
  bf16*      AGG  = (bf16*)(ws + OFF_AGG);
  bf16*      XL   = (bf16*)(ws + OFF_XL);
  _Float16*  Xh   = (_Float16*)(ws + OFF_XH);

  detect_kernel<<<1, 256, 0, stream>>>((const unsigned short*)d_in[0], flag);
  convert_kernel<<<dim3(360, NARR), 256, 0, stream>>>(ca, flag, prm);
  tohalf_kernel<<<(PRM_ELEMS + 255) / 256, 256, 0, stream>>>(prm, prmh, PRM_ELEMS);

  const float* nf   = prm + ca.off[0];
  const float* encW = prm + ca.off[1];
  const float* encb = prm + ca.off[2];

  encoder_simple<<<NODES, 128, 0, stream>>>(nf, encW, encb, Xh);
  fill_kernel<<<1, 256, 0, stream>>>(nf, fill);

  int K = 128;
  for (int L = 0; L < 3; L++) {
    const _Float16* lWh = prmh + ca.off[3 + L * 10 + 0];
    const float*    lb  = prm  + ca.off[3 + L * 10 + 1];
    const _Float16* rWh = prmh + ca.off[3 + L * 10 + 2];
    const float*    rb  = prm  + ca.off[3 + L * 10 + 3];
    const float*    att = prm  + ca.off[3 + L * 10 + 4];
    const float*    eW  = prm  + ca.off[3 + L * 10 + 5];
    const _Float16* sWh = prmh + ca.off[3 + L * 10 + 6];
    const float*    sb  = prm  + ca.off[3 + L * 10 + 7];
    const float*    g   = prm  + ca.off[3 + L * 10 + 8];
    const float*    b   = prm  + ca.off[3 + L * 10 + 9];
    gemm_xl_kernel<<<NODES / 128, 512, 0, stream>>>(Xh, K, lWh, lb, XL);
    logits_kernel<<<NODES / 128, 512, 0, stream>>>(Xh, K, rWh, rb, XL, nf, fill, att, eW, AGG);
    out_kernel<<<NODES / 128, 512, 0, stream>>>(Xh, K, sWh, sb, AGG, g, b);
    K = 256;
  }
  pool_kernel<<<BB, 256, 0, stream>>>(Xh, (float*)d_out);
}

// Round 16
// 577.682 us; speedup vs baseline: 1.1246x; 1.1246x over previous
//
#include <hip/hip_runtime.h>
#include <hip/hip_bf16.h>
#include <math.h>

#define NODES 73728   // B*T*N = 128*64*9
#define BB    128
#define TT    64
#define NN    9
#define LDX   256
#define E_REAL 203648.0f
#define NARR  33

typedef __hip_bfloat16 bf16;
typedef _Float16 half8 __attribute__((ext_vector_type(8)));
typedef _Float16 half4 __attribute__((ext_vector_type(4)));
typedef float f32x4 __attribute__((ext_vector_type(4)));

__device__ __forceinline__ float bfdec(unsigned short u) {
  return __uint_as_float(((unsigned)u) << 16);
}
__device__ __forceinline__ unsigned short f2bf(float x) {
  bf16 h = __float2bfloat16(x);
  return *(unsigned short*)&h;
}
__device__ __forceinline__ float4 ldbf4(const bf16* p) {  // 8B-aligned
  ushort4 u = *(const ushort4*)p;
  float4 f;
  f.x = bfdec(u.x); f.y = bfdec(u.y); f.z = bfdec(u.z); f.w = bfdec(u.w);
  return f;
}

// ---------------- dtype detector ----------------
__global__ __launch_bounds__(256) void detect_kernel(const unsigned short* __restrict__ raw,
                                                     float* __restrict__ flag) {
  __shared__ float sm[256];
  float mx = 0.f;
  for (int i = threadIdx.x; i < 2048; i += 256) mx = fmaxf(mx, fabsf(bfdec(raw[2 * i])));
  sm[threadIdx.x] = mx;
  __syncthreads();
  for (int s = 128; s > 0; s >>= 1) {
    if (threadIdx.x < s) sm[threadIdx.x] = fmaxf(sm[threadIdx.x], sm[threadIdx.x + s]);
    __syncthreads();
  }
  if (threadIdx.x == 0) flag[0] = (sm[0] > 1000.f) ? 1.f : 0.f;
}

// ---------------- convert all inputs to fp32 + f16 shadow in ONE pass ----------------
struct CvtArgs { const void* src[NARR]; int size[NARR]; int off[NARR]; };

__global__ __launch_bounds__(256) void convert_kernel(CvtArgs a, const float* __restrict__ flag,
                                                      float* __restrict__ dst,
                                                      _Float16* __restrict__ dsth) {
  int i = blockIdx.y;
  int sz = a.size[i];
  bool isf32 = flag[0] > 0.5f;
  const float* sf = (const float*)a.src[i];
  const unsigned short* sh = (const unsigned short*)a.src[i];
  float* d = dst + a.off[i];
  _Float16* dh = dsth + a.off[i];
  for (int j = blockIdx.x * 256 + threadIdx.x; j < sz; j += gridDim.x * 256) {
    float v = isf32 ? sf[j] : bfdec(sh[j]);
    d[j] = v;
    dh[j] = (_Float16)v;
  }
}

// ---------------- encoder (one block per node, thread d) ----------------
__global__ __launch_bounds__(128) void encoder_simple(const float* __restrict__ nf,
    const float* __restrict__ encW, const float* __restrict__ encb, _Float16* __restrict__ Xh) {
  int v = blockIdx.x, d = threadIdx.x, n = v % NN;
  float f[14];
#pragma unroll
  for (int i = 0; i < 10; i++) f[i] = nf[(size_t)v * 10 + i];
  f[10] = (n < 7) ? 1.f : 0.f;
  f[11] = (n == 7) ? 1.f : 0.f;
  f[12] = (n == 8) ? 1.f : 0.f;
  f[13] = fabsf((float)(n - 7));
  const float* w = &encW[((size_t)n * 128 + d) * 14];
  float s = encb[n * 128 + d];
#pragma unroll
  for (int i = 0; i < 14; i++) s = fmaf(f[i], w[i], s);
  Xh[(size_t)v * LDX + d] = (_Float16)s;
}

// ---------------- fill ----------------
__global__ __launch_bounds__(256) void fill_kernel(const float* __restrict__ nf,
                                                   float* __restrict__ fill) {
  __shared__ float sx[256], sy[256], sz[256];
  int tid = threadIdx.x;
  float ax = 0.f, ay = 0.f, az = 0.f;
  for (int p = tid; p < BB * NN; p += 256) {
    int b = p / NN, n = p - b * NN;
    size_t late  = (((size_t)b * TT + (TT - 1)) * NN + n) * 10;
    size_t early = (((size_t)b * TT) * NN + n) * 10;
    ax += nf[late + 0] - nf[early + 0];
    ay += nf[late + 1] - nf[early + 1];
    az += nf[late + 2] - nf[early + 2];
  }
  sx[tid] = ax; sy[tid] = ay; sz[tid] = az;
  __syncthreads();
  for (int s = 128; s > 0; s >>= 1) {
    if (tid < s) { sx[tid] += sx[tid + s]; sy[tid] += sy[tid + s]; sz[tid] += sz[tid + s]; }
    __syncthreads();
  }
  if (tid == 0) { fill[0] = sx[0] / E_REAL; fill[1] = sy[0] / E_REAL; fill[2] = sz[0] / E_REAL; }
}

// ================= MFMA GEMM (R13-proven): 64 rows x 256 cols, 256 threads =================
#define LDA 40
struct GemmSh { _Float16 A[64 * LDA]; _Float16 B[256 * LDA]; };

__device__ __forceinline__ void mfma_gemm(const _Float16* __restrict__ x,
    const _Float16* __restrict__ W, int K, int row0, int tid,
    _Float16* shA, _Float16* shB, f32x4 (&acc)[4][4]) {
  int lane = tid & 63, wv = tid >> 6;
  int quad = lane >> 4, mrow = lane & 15;
  int ar = tid >> 2, ak = (tid & 3) << 3;
  for (int k0 = 0; k0 < K; k0 += 32) {
    *(half8*)&shA[ar * LDA + ak] = *(const half8*)&x[(size_t)(row0 + ar) * LDX + k0 + ak];
#pragma unroll
    for (int j = 0; j < 4; j++)
      *(half8*)&shB[tid * LDA + (j << 3)] = *(const half8*)&W[(size_t)tid * K + k0 + (j << 3)];
    __syncthreads();
    half8 af[4], bfr[4];
#pragma unroll
    for (int rt = 0; rt < 4; rt++)
      af[rt] = *(const half8*)&shA[(rt * 16 + mrow) * LDA + quad * 8];
#pragma unroll
    for (int ct = 0; ct < 4; ct++)
      bfr[ct] = *(const half8*)&shB[(wv * 64 + ct * 16 + mrow) * LDA + quad * 8];
#pragma unroll
    for (int rt = 0; rt < 4; rt++)
#pragma unroll
      for (int ct = 0; ct < 4; ct++)
        acc[rt][ct] = __builtin_amdgcn_mfma_f32_16x16x32_f16(af[rt], bfr[ct], acc[rt][ct], 0, 0, 0);
    __syncthreads();
  }
}

// write acc (+bias) into epilogue LDS buffer as bf16.  C/D map: col=lane&15, row=quad*4+reg
#define ACC_TO_EPI(EPI, BIASPTR)                                                \
  {                                                                             \
    int lane_ = tid & 63, wv_ = tid >> 6, quad_ = lane_ >> 4, mrow_ = lane_ & 15; \
    _Pragma("unroll")                                                           \
    for (int rt = 0; rt < 4; rt++)                                              \
      _Pragma("unroll")                                                         \
      for (int ct = 0; ct < 4; ct++) {                                          \
        int col = wv_ * 64 + ct * 16 + mrow_;                                   \
        float bs_ = BIASPTR[col];                                               \
        _Pragma("unroll")                                                       \
        for (int r = 0; r < 4; r++)                                             \
          EPI[rt * 16 + quad_ * 4 + r][col] = f2bf(acc[rt][ct][r] + bs_);       \
      }                                                                         \
  }                                                                             \
  __syncthreads();

// ---------------- XL = X @ lW.T + lb -> bf16 ----------------
__global__ __launch_bounds__(256) void gemm_xl_kernel(const _Float16* __restrict__ x, int K,
    const _Float16* __restrict__ W, const float* __restrict__ bias, bf16* __restrict__ XL) {
  __shared__ union { GemmSh st; unsigned short epi[64][264]; } sh;
  int tid = threadIdx.x;
  int row0 = blockIdx.x * 64;
  f32x4 acc[4][4] = {};
  mfma_gemm(x, W, K, row0, tid, sh.st.A, sh.st.B, acc);
  ACC_TO_EPI(sh.epi, bias)
  int r = tid >> 2;
#pragma unroll
  for (int j = 0; j < 16; j++) {
    int c0 = (((tid & 3) << 4) + j) << 2;
    *(ushort4*)&XL[(size_t)(row0 + r) * LDX + c0] = *(const ushort4*)&sh.epi[r][c0];
  }
}

// ---------------- fused: XR GEMM + edge logits + softmax + aggregation -> AGG[v] bf16 ----------------
__global__ __launch_bounds__(256) void logits_kernel(const _Float16* __restrict__ x, int K,
    const _Float16* __restrict__ rW, const float* __restrict__ rb,
    const bf16* __restrict__ XL, const float* __restrict__ nf, const float* __restrict__ fill,
    const float* __restrict__ att, const float* __restrict__ eW, bf16* __restrict__ AGG) {
  __shared__ union { GemmSh st; unsigned short epi[64][264]; } sh;
  int tid = threadIdx.x;
  int row0 = blockIdx.x * 64;
  f32x4 acc[4][4] = {};
  mfma_gemm(x, rW, K, row0, tid, sh.st.A, sh.st.B, acc);
  ACC_TO_EPI(sh.epi, rb)

  int wave = tid >> 6, lane = tid & 63;
  int cc = lane << 2;        // 4 channels/lane; 16 lanes = one head
  float attv[4], ew[4][3];
#pragma unroll
  for (int i = 0; i < 4; i++) {
    attv[i] = att[cc + i];
    ew[i][0] = eW[(cc + i) * 3 + 0];
    ew[i][1] = eW[(cc + i) * 3 + 1];
    ew[i][2] = eW[(cc + i) * 3 + 2];
  }
  float f0 = fill[0], f1 = fill[1], f2 = fill[2];
  for (int k = 0; k < 16; k++) {
    int v = row0 + wave * 16 + k;
    int n = v % NN;
    int t = (v / NN) & 63;
    int srcs[4] = { v, (n > 0) ? v - 1 : v, (n < NN - 1) ? v + 1 : v, (t > 0) ? v - NN : v };
    bool valid[4] = { true, n > 0, n < NN - 1, t > 0 };
    float px = nf[(size_t)v * 10 + 0];
    float py = nf[(size_t)v * 10 + 1];
    float pz = nf[(size_t)v * 10 + 2];
    ushort4 xr4 = *(const ushort4*)&sh.epi[wave * 16 + k][cc];
    float xr[4] = { bfdec(xr4.x), bfdec(xr4.y), bfdec(xr4.z), bfdec(xr4.w) };
    float logit[4], xlv[4][4];
#pragma unroll
    for (int e = 0; e < 4; e++) {
      int s = srcs[e];
      float a0, a1, a2;
      if (e == 0) { a0 = f0; a1 = f1; a2 = f2; }
      else {
        a0 = px - nf[(size_t)s * 10 + 0];
        a1 = py - nf[(size_t)s * 10 + 1];
        a2 = pz - nf[(size_t)s * 10 + 2];
      }
      float4 xl = ldbf4(&XL[(size_t)s * LDX + cc]);
      xlv[e][0] = xl.x; xlv[e][1] = xl.y; xlv[e][2] = xl.z; xlv[e][3] = xl.w;
      float p = 0.f;
#pragma unroll
      for (int i = 0; i < 4; i++) {
        float em = fmaf(ew[i][0], a0, fmaf(ew[i][1], a1, ew[i][2] * a2));
        float mv = xlv[e][i] + xr[i] + em;
        mv = (mv > 0.f) ? mv : 0.2f * mv;   // leaky_relu 0.2
        p = fmaf(mv, attv[i], p);
      }
      p += __shfl_xor(p, 1); p += __shfl_xor(p, 2); p += __shfl_xor(p, 4); p += __shfl_xor(p, 8);
      logit[e] = valid[e] ? p : -1e30f;
    }
    float mx = fmaxf(fmaxf(logit[0], logit[1]), fmaxf(logit[2], logit[3]));
    float wv4[4], wsum = 0.f;
#pragma unroll
    for (int e = 0; e < 4; e++) { wv4[e] = __expf(logit[e] - mx); wsum += wv4[e]; }
    float inv = 1.f / wsum;
    float agg[4] = { 0.f, 0.f, 0.f, 0.f };
#pragma unroll
    for (int e = 0; e < 4; e++) {
      float w = wv4[e] * inv;                 // invalid edges: exactly 0
#pragma unroll
      for (int i = 0; i < 4; i++) agg[i] = fmaf(w, xlv[e][i], agg[i]);
    }
    ushort4 pk;
    pk.x = f2bf(agg[0]); pk.y = f2bf(agg[1]); pk.z = f2bf(agg[2]); pk.w = f2bf(agg[3]);
    *(ushort4*)&AGG[(size_t)v * LDX + cc] = pk;   // coalesced 8B/lane
  }
}

// ---------------- fused: XO = X@sW.T + bias + AGG; LN; SiLU; X f16 in-place ----------------
// do_pool: layer-2 blocks also accumulate mean-pool partials into pool_out via atomics.
__global__ __launch_bounds__(256) void out_kernel(_Float16* Xh, int K,
    const _Float16* __restrict__ sW, const float* __restrict__ bias,
    const bf16* __restrict__ AGG,
    const float* __restrict__ gamma, const float* __restrict__ beta,
    float* pool_out, int do_pool) {
  __shared__ union { GemmSh st; unsigned short epi[64][264]; float pacc[4][256]; } sh;
  int tid = threadIdx.x;
  int row0 = blockIdx.x * 64;
  f32x4 acc[4][4] = {};
  mfma_gemm(Xh, sW, K, row0, tid, sh.st.A, sh.st.B, acc);
  ACC_TO_EPI(sh.epi, bias)

  int wave = tid >> 6, lane = tid & 63;
  int cc = lane << 2;
  float gm[4], bt[4];
#pragma unroll
  for (int i = 0; i < 4; i++) { gm[i] = gamma[cc + i]; bt[i] = beta[cc + i]; }
  float psum[4] = { 0.f, 0.f, 0.f, 0.f };
  for (int k = 0; k < 16; k++) {
    int v = row0 + wave * 16 + k;
    ushort4 xo4 = *(const ushort4*)&sh.epi[wave * 16 + k][cc];
    float4 ag = ldbf4(&AGG[(size_t)v * LDX + cc]);
    float xv[4] = { bfdec(xo4.x) + ag.x, bfdec(xo4.y) + ag.y,
                    bfdec(xo4.z) + ag.z, bfdec(xo4.w) + ag.w };
    // LayerNorm over 256 channels (full-wave shuffle reduce)
    float s1 = xv[0] + xv[1] + xv[2] + xv[3];
#pragma unroll
    for (int off = 1; off < 64; off <<= 1) s1 += __shfl_xor(s1, off);
    float mu = s1 * (1.f / 256.f);
    float s2 = 0.f;
#pragma unroll
    for (int i = 0; i < 4; i++) { float d = xv[i] - mu; s2 = fmaf(d, d, s2); }
#pragma unroll
    for (int off = 1; off < 64; off <<= 1) s2 += __shfl_xor(s2, off);
    float rs = rsqrtf(s2 * (1.f / 256.f) + 1e-5f);
    half4 o;
#pragma unroll
    for (int i = 0; i < 4; i++) {
      float y = (xv[i] - mu) * rs * gm[i] + bt[i];
      float z = y * (1.f / (1.f + __expf(-y)));   // SiLU
      o[i] = (_Float16)z;
      psum[i] += z;
    }
    *(half4*)&Xh[(size_t)v * LDX + cc] = o;
  }
  if (do_pool) {
    __syncthreads();                 // epi reads done; reuse LDS as pacc
#pragma unroll
    for (int i = 0; i < 4; i++) sh.pacc[wave][cc + i] = psum[i];
    __syncthreads();
    if (wave == 0) {
      int b = row0 / 576;            // 576 = 9*64: block fully within one batch
#pragma unroll
      for (int i = 0; i < 4; i++) {
        float s = sh.pacc[0][cc + i] + sh.pacc[1][cc + i] + sh.pacc[2][cc + i] + sh.pacc[3][cc + i];
        atomicAdd(&pool_out[b * 256 + cc + i], s * (1.f / 576.f));
      }
    }
  }
}

extern "C" void kernel_launch(void* const* d_in, const int* in_sizes, int n_in,
                              void* d_out, int out_size, void* d_ws, size_t ws_size,
                              hipStream_t stream) {
  static const int kSize[NARR] = {
    737280, 16128, 1152,
    32768, 256, 32768, 256, 256, 768, 32768, 256, 256, 256,   // layer 0 (K=128)
    65536, 256, 65536, 256, 256, 768, 65536, 256, 256, 256,   // layer 1 (K=256)
    65536, 256, 65536, 256, 256, 768, 65536, 256, 256, 256    // layer 2 (K=256)
  };
  if (n_in != NARR || out_size != BB * 256) return;
  for (int i = 0; i < NARR; i++) if (in_sizes[i] != kSize[i]) return;

  CvtArgs ca;
  int off = 0;
  for (int i = 0; i < NARR; i++) { ca.src[i] = d_in[i]; ca.size[i] = kSize[i]; ca.off[i] = off; off += kSize[i]; }
  const int PRM_ELEMS = off;   // 1,252,992

  const size_t OFF_FLAG = 0;
  const size_t OFF_FILL = 16;
  const size_t OFF_PRM  = 256;
  const size_t OFF_PRMH = OFF_PRM + (size_t)PRM_ELEMS * 4;     // f16 shadow
  const size_t OFF_AGG  = OFF_PRMH + (size_t)PRM_ELEMS * 2;
  const size_t OFF_XL   = OFF_AGG + (size_t)NODES * LDX * 2;   // AGG bf16
  const size_t OFF_XH   = OFF_XL + (size_t)NODES * LDX * 2;    // XL bf16
  const size_t NEED     = OFF_XH + (size_t)NODES * LDX * 2;    // ~115 MiB (< proven 125.3)
  if (ws_size < NEED) return;

  char* ws = (char*)d_ws;
  float*     flag = (float*)(ws + OFF_FLAG);
  float*     fill = (float*)(ws + OFF_FILL);
  float*     prm  = (float*)(ws + OFF_PRM);
  _Float16*  prmh = (_Float16*)(ws + OFF_PRMH);
  bf16*      AGG  = (bf16*)(ws + OFF_AGG);
  bf16*      XL   = (bf16*)(ws + OFF_XL);
  _Float16*  Xh   = (_Float16*)(ws + OFF_XH);

  hipMemsetAsync(d_out, 0, (size_t)out_size * 4, stream);   // pool accumulator
  detect_kernel<<<1, 256, 0, stream>>>((const unsigned short*)d_in[0], flag);
  convert_kernel<<<dim3(360, NARR), 256, 0, stream>>>(ca, flag, prm, prmh);

  const float* nf   = prm + ca.off[0];
  const float* encW = prm + ca.off[1];
  const float* encb = prm + ca.off[2];

  encoder_simple<<<NODES, 128, 0, stream>>>(nf, encW, encb, Xh);
  fill_kernel<<<1, 256, 0, stream>>>(nf, fill);

  int K = 128;
  for (int L = 0; L < 3; L++) {
    const _Float16* lWh = prmh + ca.off[3 + L * 10 + 0];
    const float*    lb  = prm  + ca.off[3 + L * 10 + 1];
    const _Float16* rWh = prmh + ca.off[3 + L * 10 + 2];
    const float*    rb  = prm  + ca.off[3 + L * 10 + 3];
    const float*    att = prm  + ca.off[3 + L * 10 + 4];
    const float*    eW  = prm  + ca.off[3 + L * 10 + 5];
    const _Float16* sWh = prmh + ca.off[3 + L * 10 + 6];
    const float*    sb  = prm  + ca.off[3 + L * 10 + 7];
    const float*    g   = prm  + ca.off[3 + L * 10 + 8];
    const float*    b   = prm  + ca.off[3 + L * 10 + 9];
    gemm_xl_kernel<<<NODES / 64, 256, 0, stream>>>(Xh, K, lWh, lb, XL);
    logits_kernel<<<NODES / 64, 256, 0, stream>>>(Xh, K, rWh, rb, XL, nf, fill, att, eW, AGG);
    out_kernel<<<NODES / 64, 256, 0, stream>>>(Xh, K, sWh, sb, AGG, g, b,
                                               (float*)d_out, (L == 2) ? 1 : 0);
    K = 256;
  }
}